// Round 11
// baseline (707.168 us; speedup 1.0000x reference)
//
#include <hip/hip_runtime.h>
#include <hip/hip_bf16.h>

// Continuous convolution, round 11: software-pipelined persistent WGs.
//   512 persistent WGs x 32 voxel-groups (VX=4 each). Per iteration the
//   feats stage for group g+1 is issued fire-and-forget (global_load_lds)
//   and stays in flight across zero-B + scatter + MFMA of group g, using
//   raw s_barrier + lgkmcnt(0)-only waits (m201 pattern) so the compiler's
//   vmcnt(0)-before-barrier drain doesn't collapse the window.
//   Rationale: r2 proved the L2-miss service rate reaches 7.7G lines/s under
//   supply pressure; r6-r10 sat at 4.8G because every __syncthreads drains
//   vmcnt. Double-buffered: fstage/wls/bca/fbase/den. Single B tile.
//   Contraction: bf16 hi/lo split MFMA (3 products) vs packed W^T fragments.

typedef unsigned short u16;
typedef unsigned int   u32;
typedef __attribute__((ext_vector_type(4))) float f32x4;
typedef __attribute__((ext_vector_type(8))) short short8;

#define NOUT    65536
#define VX      4                 // voxels per group
#define THREADS 512
#define EPW     128               // edges per group
#define NGRP    (NOUT / VX)       // 16384 groups
#define GRID    512               // persistent WGs (2 per CU)
#define GP      (NGRP / GRID)     // 32 groups per WG
#define BSTRIDE 2052              // f32 words per voxel (64*32 + 4 pad)
#define VROWB   (BSTRIDE * 4)     // 8208 bytes
#define BL_BYTES (VX * VROWB)     // 32832

// LDS carve (bytes):
#define OFF_FS0  BL_BYTES               // fstage[2][128][32] f32
#define OFF_FS1  (OFF_FS0 + 16384)
#define OFF_WL0  (OFF_FS1 + 16384)      // wls[2][8][128] f32 (alias Yp)
#define OFF_WL1  (OFF_WL0 + 4096)
#define OFF_BC0  (OFF_WL1 + 4096)       // bca[2][128] u32
#define OFF_BC1  (OFF_BC0 + 512)
#define OFF_FB0  (OFF_BC1 + 512)        // fbase[2][128] int
#define OFF_FB1  (OFF_FB0 + 512)
#define OFF_DN0  (OFF_FB1 + 512)        // den[2][4] f32
#define OFF_DN1  (OFF_DN0 + 16)
#define SMEM_BYTES (OFF_DN1 + 16)       // 75872 -> 2 WG/CU

#define LGKM_BAR() do {                                        \
    asm volatile("s_waitcnt lgkmcnt(0)" ::: "memory");         \
    __builtin_amdgcn_sched_barrier(0);                         \
    __builtin_amdgcn_s_barrier();                              \
  } while (0)

// ---- prep: pack W (2048x32 f32) into MFMA B-fragment order, bf16 hi/lo ----
// wpk[tb][bin][lane][j] u16, tb: 0=hi d0-15, 1=lo d0-15, 2=hi d16-31, 3=lo.
// Lane l supplies B[kappa = bin*32 + (l>>4)*8 + j][d = (l&15) + 16*(tb>>1)].
__global__ void prep_w_kernel(const float* __restrict__ W,
                              u16* __restrict__ wpk) {
  int id  = blockIdx.x * 256 + threadIdx.x;   // 0..131071
  int j   = id & 7;
  int l   = (id >> 3) & 63;
  int bin = (id >> 9) & 63;
  int tb  = id >> 15;                         // 0..3
  int kap = (bin << 5) + ((l >> 4) << 3) + j;
  int d   = (l & 15) + ((tb >> 1) << 4);
  float w = W[kap * 32 + d];
  unsigned u = __float_as_uint(w);
  u16 val;
  if (tb & 1) {
    float rem = w - __uint_as_float(u & 0xFFFF0000u);   // exact residual
    val = (u16)(__float_as_uint(rem) >> 16);
  } else {
    val = (u16)(u >> 16);                               // truncated bf16
  }
  wpk[id] = val;
}

// geometry for group gid into buffers (threads 0..127 active)
__device__ __forceinline__ void geom_phase(
    int gid, int tid, int lane,
    const float* inp_points, const float* out_points, float inv,
    const float* scale_compat, const int* nbr_idx, bool is64,
    const float* nbr_dist,
    float* wlsq, u32* bcaq, int* fbq, float* denq) {
  if (tid >= EPW) return;
  int e  = tid;
  int v  = e >> 5;
  int gv = (gid << 2) + v;
  int ge = (gid << 7) + e;
  int idx = nbr_idx[is64 ? (ge << 1) : ge];
  float dist = nbr_dist[ge];
  float sc   = scale_compat[ge];
  float om = 1.f - dist * dist;
  om = fminf(fmaxf(om, 0.f), 1.f);
  float a = sc * om * om * om;
  float ox = out_points[gv * 3 + 0];
  float oy = out_points[gv * 3 + 1];
  float oz = out_points[gv * 3 + 2];
  float rx = (inp_points[idx * 3 + 0] - ox) * inv;
  float ry = (inp_points[idx * 3 + 1] - oy) * inv;
  float rz = (inp_points[idx * 3 + 2] - oz) * inv;
  float n2   = sqrtf(rx * rx + ry * ry + rz * rz + 1e-12f);
  float ninf = fmaxf(fabsf(rx), fmaxf(fabsf(ry), fabsf(rz)));
  float scl  = (ninf > 1e-8f) ? (n2 / ninf) : 0.f;
  float cx = fminf(fmaxf(rx * scl, -1.f), 1.f);
  float cy = fminf(fmaxf(ry * scl, -1.f), 1.f);
  float cz = fminf(fmaxf(rz * scl, -1.f), 1.f);
  float ux = fminf(fmaxf((cx + 1.f) * 1.5f, 0.f), 3.f);
  float uy = fminf(fmaxf((cy + 1.f) * 1.5f, 0.f), 3.f);
  float uz = fminf(fmaxf((cz + 1.f) * 1.5f, 0.f), 3.f);
  float fx = fminf(floorf(ux), 2.f);
  float fy = fminf(floorf(uy), 2.f);
  float fz = fminf(floorf(uz), 2.f);
  float tx = ux - fx, ty = uy - fy, tz = uz - fz;
  int ix = (int)fx, iy = (int)fy, iz = (int)fz;
  float X1 = tx * a, X0 = a - X1;             // fold importance into x weights
  float Y1 = ty,     Y0 = 1.f - ty;
  float Z1 = tz,     Z0 = 1.f - tz;
  float p00 = X0 * Y0, p01 = X0 * Y1, p10 = X1 * Y0, p11 = X1 * Y1;
  float wc[8];
  wc[0] = p00 * Z0; wc[1] = p00 * Z1; wc[2] = p01 * Z0; wc[3] = p01 * Z1;
  wc[4] = p10 * Z0; wc[5] = p10 * Z1; wc[6] = p11 * Z0; wc[7] = p11 * Z1;
  int kb = (ix * 4 + iy) * 4 + iz;            // base bin (<=42)
  u32 bb = (u32)(v * VROWB + (kb << 7));      // < 32768
  int nc = 0; u32 mask = 0;
  #pragma unroll
  for (int k = 0; k < 8; ++k) {
    if (wc[k] != 0.f) {
      wlsq[nc * EPW + e] = wc[k];
      mask |= (1u << k);
      ++nc;
    }
  }
  bcaq[e] = bb | (mask << 16) | ((u32)nc << 24);
  fbq[e]  = idx;                              // feats ROW index
  float s = a;                                // per-voxel denom (32 lanes/vox)
  s += __shfl_xor(s, 1);
  s += __shfl_xor(s, 2);
  s += __shfl_xor(s, 4);
  s += __shfl_xor(s, 8);
  s += __shfl_xor(s, 16);
  if ((lane & 31) == 0) denq[v] = s;
}

__launch_bounds__(THREADS, 4)
__global__ void cconv_kernel(const float* __restrict__ feats,
                             const float* __restrict__ inp_points,
                             const float* __restrict__ out_points,
                             const float* __restrict__ out_extents,
                             const float* __restrict__ scale_compat,
                             const int*   __restrict__ nbr_idx,
                             const int*   __restrict__ row_splits,
                             const float* __restrict__ nbr_dist,
                             const float* __restrict__ bias,
                             const u16*   __restrict__ wpk,
                             float*       __restrict__ out) {
  extern __shared__ __align__(16) char smem[];

  const int tid  = threadIdx.x;
  const int bid  = blockIdx.x;
  const int lane = tid & 63;
  const int wv   = tid >> 6;                  // wave 0..7
  const bool is64 = (row_splits[1] == 0);
  const float inv = 2.f / out_extents[0];
  const int c  = tid & 31;                    // channel
  const int e0 = tid >> 5;                    // 0..15

  // ---- prologue: geometry(group bid) into buf0, stage(bid) into fstage0 ----
  geom_phase(bid, tid, lane, inp_points, out_points, inv, scale_compat,
             nbr_idx, is64, nbr_dist,
             (float*)(smem + OFF_WL0), (u32*)(smem + OFF_BC0),
             (int*)(smem + OFF_FB0), (float*)(smem + OFF_DN0));
  __syncthreads();
  {
    const int* fb0 = (const int*)(smem + OFF_FB0);
    #pragma unroll
    for (int rd = 0; rd < 2; ++rd) {
      int t = (rd << 9) + tid;                // 0..1023
      int r = t >> 3;
      int k = t & 7;
      const float* g = feats + ((size_t)fb0[r] << 5) + (k << 2);
      __builtin_amdgcn_global_load_lds(
          (const __attribute__((address_space(1))) void*)(const void*)g,
          (__attribute__((address_space(3))) void*)(void*)(smem + OFF_FS0 + (t << 4)),
          16, 0, 0);
    }
  }

  int p = 0;
  for (int it2 = 0; it2 < GP; ++it2) {
    const int gid = it2 * GRID + bid;
    const int q   = p ^ 1;
    char* fs_p = smem + (p ? OFF_FS1 : OFF_FS0);
    char* fs_q = smem + (q ? OFF_FS1 : OFF_FS0);
    float* wls_p = (float*)(smem + (p ? OFF_WL1 : OFF_WL0));
    float* Yp    = wls_p;                     // alias after scatter done
    u32*  bca_p  = (u32*)(smem + (p ? OFF_BC1 : OFF_BC0));
    float* den_p = (float*)(smem + (p ? OFF_DN1 : OFF_DN0));

    __syncthreads();   // drains vmcnt: stage(gid) complete in fs_p

    // ---- pull this thread's 8 feats values LDS -> regs ----
    float fg[8];
    {
      const float* fs = (const float*)fs_p;
      #pragma unroll
      for (int it = 0; it < 8; ++it)
        fg[it] = fs[(((it << 4) + e0) << 5) + c];
    }

    // ---- geometry for next group into q buffers ----
    if (it2 + 1 < GP) {
      geom_phase(gid + GRID, tid, lane, inp_points, out_points, inv,
                 scale_compat, nbr_idx, is64, nbr_dist,
                 (float*)(smem + (q ? OFF_WL1 : OFF_WL0)),
                 (u32*)(smem + (q ? OFF_BC1 : OFF_BC0)),
                 (int*)(smem + (q ? OFF_FB1 : OFF_FB0)),
                 (float*)(smem + (q ? OFF_DN1 : OFF_DN0)));
    }
    __syncthreads();   // fbase[q] visible; nothing vm in flight here

    // ---- issue stage(next) fire-and-forget; rides through raw barriers ----
    if (it2 + 1 < GP) {
      const int* fbq = (const int*)(smem + (q ? OFF_FB1 : OFF_FB0));
      #pragma unroll
      for (int rd = 0; rd < 2; ++rd) {
        int t = (rd << 9) + tid;
        int r = t >> 3;
        int k = t & 7;
        const float* g = feats + ((size_t)fbq[r] << 5) + (k << 2);
        __builtin_amdgcn_global_load_lds(
            (const __attribute__((address_space(1))) void*)(const void*)g,
            (__attribute__((address_space(3))) void*)(void*)(fs_q + (t << 4)),
            16, 0, 0);
      }
    }

    // ---- zero B tile ----
    {
      f32x4 z = {0.f, 0.f, 0.f, 0.f};
      for (int i = tid; i < (BL_BYTES / 16); i += THREADS)
        ((f32x4*)smem)[i] = z;
    }
    LGKM_BAR();   // LDS-only fence: B zero visible; stage stays in flight

    // ---- scatter: lane=channel, half-wave=edge row ----
    {
      #pragma unroll
      for (int it = 0; it < 8; ++it) {
        int   e    = (it << 4) + e0;
        u32   m    = bca_p[e];
        u32   base = (m & 0xFFFFu) + ((u32)c << 2);
        u32   mask = (m >> 16) & 0xFFu;
        int   nc   = (int)(m >> 24);
        float f    = fg[it];
        for (int j = 0; j < nc; ++j) {        // ~2-3 iters, uniform per edge
          float w = wls_p[j * EPW + e];       // broadcast within half-wave
          int   k = __builtin_ctz(mask);
          mask &= mask - 1;
          u32 d = ((k & 1) << 7) | ((k & 2) << 8) | ((k & 4) << 9);
          atomicAdd((float*)(smem + base + d), w * f);  // banks 0..31
        }
      }
    }
    LGKM_BAR();   // atomics (DS) done; stage still in flight

    // ---- MFMA contraction: wave wv owns bins [8*wv, 8*wv+8) ----
    f32x4 acc0 = {0.f, 0.f, 0.f, 0.f};        // cout 0..15
    f32x4 acc1 = {0.f, 0.f, 0.f, 0.f};        // cout 16..31
    {
      const short8* wp = (const short8*)wpk;  // [4][64][64] fragments
      int v16 = lane & 15;                    // A row (rows 4-15 dup of 0-3)
      int qq  = lane >> 4;
      const char* arow = smem + (size_t)(v16 & 3) * VROWB;
      #pragma unroll
      for (int b = 0; b < 8; ++b) {
        int bin = (wv << 3) + b;
        short8 w0h = wp[((0 * 64 + bin) << 6) + lane];
        short8 w0l = wp[((1 * 64 + bin) << 6) + lane];
        short8 w1h = wp[((2 * 64 + bin) << 6) + lane];
        short8 w1l = wp[((3 * 64 + bin) << 6) + lane];
        const float* ap = (const float*)(arow + (bin << 7) + (qq << 5));
        f32x4 a0 = *(const f32x4*)ap;         // ch k0..k0+3
        f32x4 a1 = *(const f32x4*)(ap + 4);   // ch k0+4..k0+7
        short8 ahi, alo;
        #pragma unroll
        for (int j = 0; j < 4; ++j) {
          unsigned u0 = __float_as_uint(a0[j]);
          ahi[j] = (short)(u0 >> 16);
          float r0 = a0[j] - __uint_as_float(u0 & 0xFFFF0000u);
          alo[j] = (short)(__float_as_uint(r0) >> 16);
          unsigned u1 = __float_as_uint(a1[j]);
          ahi[j + 4] = (short)(u1 >> 16);
          float r1 = a1[j] - __uint_as_float(u1 & 0xFFFF0000u);
          alo[j + 4] = (short)(__float_as_uint(r1) >> 16);
        }
        acc0 = __builtin_amdgcn_mfma_f32_16x16x32_bf16(ahi, w0h, acc0, 0, 0, 0);
        acc0 = __builtin_amdgcn_mfma_f32_16x16x32_bf16(ahi, w0l, acc0, 0, 0, 0);
        acc0 = __builtin_amdgcn_mfma_f32_16x16x32_bf16(alo, w0h, acc0, 0, 0, 0);
        acc1 = __builtin_amdgcn_mfma_f32_16x16x32_bf16(ahi, w1h, acc1, 0, 0, 0);
        acc1 = __builtin_amdgcn_mfma_f32_16x16x32_bf16(ahi, w1l, acc1, 0, 0, 0);
        acc1 = __builtin_amdgcn_mfma_f32_16x16x32_bf16(alo, w1h, acc1, 0, 0, 0);
      }
    }

    // ---- out: per-wave partials -> reduce -> normalize/bias/relu/store ----
    // C/D layout: col = lane&15 (cout), row = (lane>>4)*4 + reg (voxel)
    if (lane < 16) {
      float* yp = Yp + (wv << 7);             // 4 v x 32 d per wave
      #pragma unroll
      for (int r = 0; r < 4; ++r) {
        yp[r * 32 + lane]      = acc0[r];
        yp[r * 32 + 16 + lane] = acc1[r];
      }
    }
    LGKM_BAR();   // Yp writes visible; stage (if still pending) unaffected
    if (tid < EPW) {
      float s = 0.f;
      #pragma unroll
      for (int w = 0; w < 8; ++w) s += Yp[(w << 7) + tid];
      int v = tid >> 5;
      int d = tid & 31;
      float dn = fmaxf(den_p[v], 1e-8f);
      float y = s / dn + bias[d];
      out[(gid << 7) + tid] = fmaxf(y, 0.f);
    }
    p = q;
  }
}

extern "C" void kernel_launch(void* const* d_in, const int* in_sizes, int n_in,
                              void* d_out, int out_size, void* d_ws, size_t ws_size,
                              hipStream_t stream) {
  const float* feats        = (const float*)d_in[0];
  const float* inp_points   = (const float*)d_in[1];
  const float* out_points   = (const float*)d_in[2];
  const float* out_extents  = (const float*)d_in[3];
  const float* scale_compat = (const float*)d_in[4];
  const int*   nbr_idx      = (const int*)d_in[5];
  const int*   row_splits   = (const int*)d_in[6];
  const float* nbr_dist     = (const float*)d_in[7];
  const float* W            = (const float*)d_in[8];
  const float* bias         = (const float*)d_in[9];

  u16* wpk = (u16*)d_ws;                // [4][64][64][8] u16 = 256 KiB

  static_assert(SMEM_BYTES <= 81920, "LDS over 2-per-CU budget");
  (void)hipFuncSetAttribute((const void*)cconv_kernel,
                            hipFuncAttributeMaxDynamicSharedMemorySize,
                            SMEM_BYTES);

  prep_w_kernel<<<512, 256, 0, stream>>>(W, wpk);
  cconv_kernel<<<GRID, THREADS, SMEM_BYTES, stream>>>(
      feats, inp_points, out_points, out_extents, scale_compat, nbr_idx,
      row_splits, nbr_dist, bias, wpk, (float*)d_out);
}

// Round 12
// 624.229 us; speedup vs baseline: 1.1329x; 1.1329x over previous
//
#include <hip/hip_runtime.h>
#include <hip/hip_bf16.h>

// Continuous convolution, round 12: max-concurrency gather burst.
//   WG = 8 voxels (256 edges), 512 threads, LDS 74.9 KB -> 2 WG/CU.
//   One unsegmented stage: 256 full feats rows (32 KB) via 4 back-to-back
//   global_load_lds instrs/thread = 512 lines in flight per WG, ~1024/CU
//   (r6 had ~64: r11 post-mortem found in-order vmcnt made every other
//   design's effective concurrency tiny). No other vmem between stage issue
//   and its drain barrier. If this doesn't move, the ~330 GB/s random-line
//   service rate is a hardware wall -> roofline.
//   Rest = r6's verified structure: wls/bca LDS, half-wave conflict-free
//   scatter, bf16 hi/lo split MFMA (3 products) vs packed W^T fragments.

typedef unsigned short u16;
typedef unsigned int   u32;
typedef __attribute__((ext_vector_type(4))) float f32x4;
typedef __attribute__((ext_vector_type(8))) short short8;

#define NOUT    65536
#define VX      8               // voxels per WG
#define THREADS 512
#define EPW     256             // edges per WG
#define NWG     (NOUT / VX)     // 8192
#define BSTRIDE 2052            // f32 words per voxel (64 bins * 32 ch + 4 pad)
#define VROWB   (BSTRIDE * 4)   // 8208 bytes
#define BL_BYTES (VX * VROWB)   // 65664 (fstage [256][32] f32 aliases first 32KB)

// LDS carve (bytes):
#define OFF_W   BL_BYTES              // wls [8][256] f32 (alias Yp 8KB)
#define OFF_BCA (OFF_W + 8*EPW*4)     // bca [256] u32 (bb | mask<<16 | nc<<24)
#define OFF_DEN (OFF_BCA + EPW*4)     // den [8] f32
#define SMEM_BYTES (OFF_DEN + 32)     // 74912 -> 2 WG/CU

// ---- prep: pack W (2048x32 f32) into MFMA B-fragment order, bf16 hi/lo ----
// wpk[tb][bin][lane][j] u16, tb: 0=hi d0-15, 1=lo d0-15, 2=hi d16-31, 3=lo.
// Lane l supplies B[kappa = bin*32 + (l>>4)*8 + j][d = (l&15) + 16*(tb>>1)].
__global__ void prep_w_kernel(const float* __restrict__ W,
                              u16* __restrict__ wpk) {
  int id  = blockIdx.x * 256 + threadIdx.x;   // 0..131071
  int j   = id & 7;
  int l   = (id >> 3) & 63;
  int bin = (id >> 9) & 63;
  int tb  = id >> 15;                         // 0..3
  int kap = (bin << 5) + ((l >> 4) << 3) + j;
  int d   = (l & 15) + ((tb >> 1) << 4);
  float w = W[kap * 32 + d];
  unsigned u = __float_as_uint(w);
  u16 val;
  if (tb & 1) {
    float rem = w - __uint_as_float(u & 0xFFFF0000u);   // exact residual
    val = (u16)(__float_as_uint(rem) >> 16);
  } else {
    val = (u16)(u >> 16);                               // truncated bf16
  }
  wpk[id] = val;
}

__launch_bounds__(THREADS, 4)   // 16 waves/CU (2 WGs), VGPR cap 128
__global__ void cconv_kernel(const float* __restrict__ feats,
                             const float* __restrict__ inp_points,
                             const float* __restrict__ out_points,
                             const float* __restrict__ out_extents,
                             const float* __restrict__ scale_compat,
                             const int*   __restrict__ nbr_idx,
                             const int*   __restrict__ row_splits,
                             const float* __restrict__ nbr_dist,
                             const float* __restrict__ bias,
                             const u16*   __restrict__ wpk,
                             float*       __restrict__ out) {
  extern __shared__ __align__(16) char smem[];
  float* wls = (float*)(smem + OFF_W);
  float* Yp  = wls;                           // alias after scatter done
  u32*   bca = (u32*)(smem + OFF_BCA);
  float* den = (float*)(smem + OFF_DEN);

  const int tid  = threadIdx.x;
  const int wg   = blockIdx.x;
  const int lane = tid & 63;
  const int wv   = tid >> 6;                  // wave 0..7

  int fb_idx = -1;                            // this thread's edge row index

  // ---- geometry: one edge per thread (threads 0..255) ----
  if (tid < EPW) {
    const bool is64 = (row_splits[1] == 0);   // int32 view of int64 splits
    int e  = tid;
    int v  = e >> 5;
    int gv = (wg << 3) + v;
    int ge = (wg << 8) + e;
    int idx = nbr_idx[is64 ? (ge << 1) : ge];
    fb_idx = idx;
    float dist = nbr_dist[ge];
    float sc   = scale_compat[ge];
    float om = 1.f - dist * dist;
    om = fminf(fmaxf(om, 0.f), 1.f);
    float a = sc * om * om * om;
    float inv = 2.f / out_extents[0];
    float ox = out_points[gv * 3 + 0];
    float oy = out_points[gv * 3 + 1];
    float oz = out_points[gv * 3 + 2];
    float rx = (inp_points[idx * 3 + 0] - ox) * inv;
    float ry = (inp_points[idx * 3 + 1] - oy) * inv;
    float rz = (inp_points[idx * 3 + 2] - oz) * inv;
    float n2   = sqrtf(rx * rx + ry * ry + rz * rz + 1e-12f);
    float ninf = fmaxf(fabsf(rx), fmaxf(fabsf(ry), fabsf(rz)));
    float scl  = (ninf > 1e-8f) ? (n2 / ninf) : 0.f;
    float cx = fminf(fmaxf(rx * scl, -1.f), 1.f);
    float cy = fminf(fmaxf(ry * scl, -1.f), 1.f);
    float cz = fminf(fmaxf(rz * scl, -1.f), 1.f);
    float ux = fminf(fmaxf((cx + 1.f) * 1.5f, 0.f), 3.f);
    float uy = fminf(fmaxf((cy + 1.f) * 1.5f, 0.f), 3.f);
    float uz = fminf(fmaxf((cz + 1.f) * 1.5f, 0.f), 3.f);
    float fx = fminf(floorf(ux), 2.f);
    float fy = fminf(floorf(uy), 2.f);
    float fz = fminf(floorf(uz), 2.f);
    float tx = ux - fx, ty = uy - fy, tz = uz - fz;
    int ix = (int)fx, iy = (int)fy, iz = (int)fz;
    float X1 = tx * a, X0 = a - X1;           // fold importance into x weights
    float Y1 = ty,     Y0 = 1.f - ty;
    float Z1 = tz,     Z0 = 1.f - tz;
    float p00 = X0 * Y0, p01 = X0 * Y1, p10 = X1 * Y0, p11 = X1 * Y1;
    float wc[8];
    wc[0] = p00 * Z0; wc[1] = p00 * Z1; wc[2] = p01 * Z0; wc[3] = p01 * Z1;
    wc[4] = p10 * Z0; wc[5] = p10 * Z1; wc[6] = p11 * Z0; wc[7] = p11 * Z1;
    int kb = (ix * 4 + iy) * 4 + iz;          // base bin (<=42)
    u32 bb = (u32)(v * VROWB + (kb << 7));    // <= 62944, fits 16 bits
    int nc = 0; u32 mask = 0;
    #pragma unroll
    for (int k = 0; k < 8; ++k) {
      if (wc[k] != 0.f) {
        wls[nc * EPW + e] = wc[k];
        mask |= (1u << k);
        ++nc;
      }
    }
    bca[e] = bb | (mask << 16) | ((u32)nc << 24);
    // stash row index in bca-adjacent trick: reuse fstage word 0 region is
    // unsafe pre-stage; instead broadcast via LDS den? -> use dedicated slot:
    // write to wls tail is occupied; simplest: store into Yp? same as wls.
    // Use the B region (not yet staged/zeroed): first 256 ints.
    ((int*)smem)[10240 + e] = idx;            // bytes 40960.. : above fstage(32KB)
    // per-voxel denom: half-wave (32 lanes = 1 voxel) shuffle reduction
    float s = a;
    s += __shfl_xor(s, 1);
    s += __shfl_xor(s, 2);
    s += __shfl_xor(s, 4);
    s += __shfl_xor(s, 8);
    s += __shfl_xor(s, 16);
    if ((lane & 31) == 0) den[v] = s;
  }
  __syncthreads();

  // ---- ONE max-concurrency stage burst: 256 rows (32KB) into fstage ----
  // Chunk t (0..2047): row r = t>>3, 16B piece k = t&7; dest = smem + t*16.
  // 4 back-to-back instrs/thread, no other vmem until the drain barrier:
  // 512 lines in flight per WG (~1024/CU with 2 WGs).
  {
    const int* fbl = (const int*)smem + 10240;  // row indices (above fstage)
    #pragma unroll
    for (int rd = 0; rd < 4; ++rd) {
      int t = (rd << 9) + tid;
      int r = t >> 3;
      int k = t & 7;
      const float* g = feats + ((size_t)fbl[r] << 5) + (k << 2);
      __builtin_amdgcn_global_load_lds(
          (const __attribute__((address_space(1))) void*)(const void*)g,
          (__attribute__((address_space(3))) void*)(void*)(smem + (t << 4)),
          16, 0, 0);
    }
  }
  __syncthreads();   // drains vmcnt: all 512 lines landed

  // ---- pull this thread's 16 feats values LDS -> regs ----
  const int c  = tid & 31;                    // channel
  const int e0 = tid >> 5;                    // 0..15
  float fg[16];
  {
    const float* fs = (const float*)smem;
    #pragma unroll
    for (int it = 0; it < 16; ++it)           // bank = c: 2-way across wave
      fg[it] = fs[(((it << 4) + e0) << 5) + c];
  }
  __syncthreads();   // everyone done reading fstage

  // ---- zero B tile (overwrites fstage alias) ----
  {
    f32x4 z = {0.f, 0.f, 0.f, 0.f};
    for (int i = tid; i < (BL_BYTES / 16); i += THREADS)
      ((f32x4*)smem)[i] = z;
  }
  __syncthreads();

  // ---- scatter: lane=channel, half-wave=edge row ----
  {
    #pragma unroll
    for (int it = 0; it < 16; ++it) {
      int   e    = (it << 4) + e0;
      u32   m    = bca[e];
      u32   base = (m & 0xFFFFu) + ((u32)c << 2);
      u32   mask = (m >> 16) & 0xFFu;
      int   nc   = (int)(m >> 24);
      float f    = fg[it];
      for (int j = 0; j < nc; ++j) {          // ~2-3 iters, uniform per edge
        float w = wls[j * EPW + e];           // broadcast within half-wave
        int   k = __builtin_ctz(mask);
        mask &= mask - 1;
        u32 d = ((k & 1) << 7) | ((k & 2) << 8) | ((k & 4) << 9);
        atomicAdd((float*)(smem + base + d), w * f);  // banks 0..31, <=2-way
      }
    }
  }
  __syncthreads();

  // ---- MFMA contraction: wave wv owns bins [8*wv, 8*wv+8) ----
  f32x4 acc0 = {0.f, 0.f, 0.f, 0.f};          // cout 0..15
  f32x4 acc1 = {0.f, 0.f, 0.f, 0.f};          // cout 16..31
  {
    const short8* wp = (const short8*)wpk;    // [4][64][64] fragments
    int v16 = lane & 15;                      // A row (rows 8-15 dup of 0-7)
    int q   = lane >> 4;
    const char* arow = smem + (size_t)(v16 & 7) * VROWB;
    #pragma unroll
    for (int b = 0; b < 8; ++b) {
      int bin = (wv << 3) + b;
      short8 w0h = wp[((0 * 64 + bin) << 6) + lane];
      short8 w0l = wp[((1 * 64 + bin) << 6) + lane];
      short8 w1h = wp[((2 * 64 + bin) << 6) + lane];
      short8 w1l = wp[((3 * 64 + bin) << 6) + lane];
      const float* ap = (const float*)(arow + (bin << 7) + (q << 5));
      f32x4 a0 = *(const f32x4*)ap;           // ch k0..k0+3
      f32x4 a1 = *(const f32x4*)(ap + 4);     // ch k0+4..k0+7
      short8 ahi, alo;
      #pragma unroll
      for (int j = 0; j < 4; ++j) {
        unsigned u0 = __float_as_uint(a0[j]);
        ahi[j] = (short)(u0 >> 16);
        float r0 = a0[j] - __uint_as_float(u0 & 0xFFFF0000u);
        alo[j] = (short)(__float_as_uint(r0) >> 16);
        unsigned u1 = __float_as_uint(a1[j]);
        ahi[j + 4] = (short)(u1 >> 16);
        float r1 = a1[j] - __uint_as_float(u1 & 0xFFFF0000u);
        alo[j + 4] = (short)(__float_as_uint(r1) >> 16);
      }
      acc0 = __builtin_amdgcn_mfma_f32_16x16x32_bf16(ahi, w0h, acc0, 0, 0, 0);
      acc0 = __builtin_amdgcn_mfma_f32_16x16x32_bf16(ahi, w0l, acc0, 0, 0, 0);
      acc0 = __builtin_amdgcn_mfma_f32_16x16x32_bf16(alo, w0h, acc0, 0, 0, 0);
      acc1 = __builtin_amdgcn_mfma_f32_16x16x32_bf16(ahi, w1h, acc1, 0, 0, 0);
      acc1 = __builtin_amdgcn_mfma_f32_16x16x32_bf16(ahi, w1l, acc1, 0, 0, 0);
      acc1 = __builtin_amdgcn_mfma_f32_16x16x32_bf16(alo, w1h, acc1, 0, 0, 0);
    }
  }
  __syncthreads();   // all A-reads of B done; safe to alias Yp over wls

  // ---- per-wave partials: valid C rows 0..7 live in lanes 0..31 ----
  // C/D layout: col = lane&15 (cout), row = (lane>>4)*4 + reg (voxel)
  if (lane < 32) {
    float* yp = Yp + (wv << 8);               // 8 v x 32 d per wave
    int v0 = (lane >> 4) << 2;
    int d0 = lane & 15;
    #pragma unroll
    for (int r = 0; r < 4; ++r) {
      yp[(v0 + r) * 32 + d0]      = acc0[r];
      yp[(v0 + r) * 32 + 16 + d0] = acc1[r];
    }
  }
  __syncthreads();

  // ---- reduce 8 wave-partials, normalize, bias, relu, store ----
  if (tid < EPW) {
    float s = 0.f;
    #pragma unroll
    for (int w = 0; w < 8; ++w) s += Yp[(w << 8) + tid];
    int v = tid >> 5;
    int d = tid & 31;
    float dn = fmaxf(den[v], 1e-8f);
    float y = s / dn + bias[d];
    out[(wg << 8) + tid] = fmaxf(y, 0.f);
  }
}

extern "C" void kernel_launch(void* const* d_in, const int* in_sizes, int n_in,
                              void* d_out, int out_size, void* d_ws, size_t ws_size,
                              hipStream_t stream) {
  const float* feats        = (const float*)d_in[0];
  const float* inp_points   = (const float*)d_in[1];
  const float* out_points   = (const float*)d_in[2];
  const float* out_extents  = (const float*)d_in[3];
  const float* scale_compat = (const float*)d_in[4];
  const int*   nbr_idx      = (const int*)d_in[5];
  const int*   row_splits   = (const int*)d_in[6];
  const float* nbr_dist     = (const float*)d_in[7];
  const float* W            = (const float*)d_in[8];
  const float* bias         = (const float*)d_in[9];

  u16* wpk = (u16*)d_ws;                // [4][64][64][8] u16 = 256 KiB

  static_assert(SMEM_BYTES <= 81920, "LDS over 2-per-CU budget");
  (void)hipFuncSetAttribute((const void*)cconv_kernel,
                            hipFuncAttributeMaxDynamicSharedMemorySize,
                            SMEM_BYTES);

  prep_w_kernel<<<512, 256, 0, stream>>>(W, wpk);
  cconv_kernel<<<NWG, THREADS, SMEM_BYTES, stream>>>(
      feats, inp_points, out_points, out_extents, scale_compat, nbr_idx,
      row_splits, nbr_dist, bias, wpk, (float*)d_out);
}